// Round 1
// baseline (562.258 us; speedup 1.0000x reference)
//
#include <hip/hip_runtime.h>
#include <hip/hip_bf16.h>

#define N_   32
#define C_   2048
#define ST_  16
#define H_   64      // ST*ALPHA
#define K_   3
#define CB_  512
#define LT_  400
#define LTP_ 402     // padded t rows (1 zero row each side)

using bf16x8 = __attribute__((ext_vector_type(8))) __bf16;
using f32x4  = __attribute__((ext_vector_type(4))) float;
typedef unsigned short ushort_t;

__device__ __forceinline__ unsigned short f2bf(float f) {
    unsigned int u = __float_as_uint(f);
    u = (u + 0x7fffu + ((u >> 16) & 1u)) >> 16;
    return (unsigned short)u;
}
__device__ __forceinline__ float bf2f(unsigned short h) {
    return __uint_as_float(((unsigned int)h) << 16);
}

// ---------------- P0: global branch -> per-(n,c) softmax kernel [NC,4] fp32
__global__ __launch_bounds__(256) void k_global(
    const float* __restrict__ st, const float* __restrict__ g_w1,
    const float* __restrict__ gam, const float* __restrict__ bet,
    const float* __restrict__ mean, const float* __restrict__ var,
    const float* __restrict__ g_w2, float* __restrict__ kern) {
    __shared__ float w1[H_][ST_];
    __shared__ float sc[H_], bi[H_];
    __shared__ float w2[K_][H_];
    int tid = threadIdx.x;
    for (int i = tid; i < H_ * ST_; i += 256) w1[i / ST_][i % ST_] = g_w1[i];
    if (tid < H_) {
        float s = gam[tid] * rsqrtf(var[tid] + 1e-5f);
        sc[tid] = s;
        bi[tid] = bet[tid] - mean[tid] * s;
    }
    for (int i = tid; i < K_ * H_; i += 256) w2[i / H_][i % H_] = g_w2[i];
    __syncthreads();
    int row = blockIdx.x * 256 + tid;  // n*C + c
    const float* p = st + (size_t)row * ST_;
    float s[ST_];
#pragma unroll
    for (int i = 0; i < ST_; ++i) s[i] = p[i];
    float lg0 = 0.f, lg1 = 0.f, lg2 = 0.f;
    for (int j = 0; j < H_; ++j) {
        float h = 0.f;
#pragma unroll
        for (int i = 0; i < ST_; ++i) h = fmaf(w1[j][i], s[i], h);
        h = fmaxf(fmaf(h, sc[j], bi[j]), 0.f);
        lg0 = fmaf(w2[0][j], h, lg0);
        lg1 = fmaf(w2[1][j], h, lg1);
        lg2 = fmaf(w2[2][j], h, lg2);
    }
    float m = fmaxf(lg0, fmaxf(lg1, lg2));
    float e0 = __expf(lg0 - m), e1 = __expf(lg1 - m), e2 = __expf(lg2 - m);
    float inv = 1.f / (e0 + e1 + e2);
    float4 o = make_float4(e0 * inv, e1 * inv, e2 * inv, 0.f);
    *(float4*)(kern + (size_t)row * 4) = o;
}

// ---------------- P1: transpose lt [n][c][t] fp32 -> ltT [n][t+1][c] bf16
__global__ __launch_bounds__(256) void k_transpose(
    const float* __restrict__ lt, ushort_t* __restrict__ ltT) {
    __shared__ float tile[32][33];
    int tt = blockIdx.x * 32;
    int cc = blockIdx.y * 32;
    int n  = blockIdx.z;
    const float* src = lt + ((size_t)n * C_ + cc) * LT_;
    int tx = threadIdx.x & 31, ty = threadIdx.x >> 5;  // ty 0..7
#pragma unroll
    for (int i = 0; i < 4; ++i) {
        int c = ty + i * 8;
        int t = tt + tx;
        tile[c][tx] = (t < LT_) ? src[(size_t)c * LT_ + t] : 0.f;
    }
    __syncthreads();
    ushort_t* dst = ltT + (size_t)n * LTP_ * C_;
#pragma unroll
    for (int i = 0; i < 4; ++i) {
        int tl = ty + i * 8;
        int t = tt + tl;
        if (t < LT_) dst[(size_t)(t + 1) * C_ + cc + tx] = f2bf(tile[tx][tl]);
    }
}

// zero the two pad rows of ltT
__global__ __launch_bounds__(256) void k_zero(ushort_t* __restrict__ ltT) {
    int i = blockIdx.x * 256 + threadIdx.x;  // over N*C
    int n = i >> 11, c = i & (C_ - 1);
    size_t base = (size_t)n * LTP_ * C_;
    ltT[base + c] = 0;
    ltT[base + (size_t)(LTP_ - 1) * C_ + c] = 0;
}

// ---------------- P2: repack l_w1 [cb][c][k] -> w1b[k][cb][c] bf16
__global__ __launch_bounds__(256) void k_w1(
    const float* __restrict__ l_w1, ushort_t* __restrict__ w1b) {
    int i = blockIdx.x * 256 + threadIdx.x;  // over CB*C
    float a = l_w1[(size_t)i * 3 + 0];
    float b = l_w1[(size_t)i * 3 + 1];
    float c = l_w1[(size_t)i * 3 + 2];
    w1b[0 * (size_t)CB_ * C_ + i] = f2bf(a);
    w1b[1 * (size_t)CB_ * C_ + i] = f2bf(b);
    w1b[2 * (size_t)CB_ * C_ + i] = f2bf(c);
}

// ---------------- P3: convert l_w2 [c][cb] -> bf16
__global__ __launch_bounds__(256) void k_w2(
    const float* __restrict__ l_w2, ushort_t* __restrict__ w2b) {
    int i = blockIdx.x * 256 + threadIdx.x;  // over C*CB
    w2b[i] = f2bf(l_w2[i]);
}

// ---------------- G1: Xt[n][t][cb] = ReLU(BN(sum_k W1k @ lt_shift_k)), bf16 out
// M = t (tile 80), N = cb (tile 64), K = c (BK 32), 3 taps via shifted A rows.
#define TM1 80
#define TN1 64
#define BK  32
#define AST 40  // padded LDS stride (ushorts): 80B rows -> 16B-aligned, <=2-way conflicts

__global__ __launch_bounds__(256) void k_gemm1(
    const ushort_t* __restrict__ ltT, const ushort_t* __restrict__ w1b,
    const float* __restrict__ bn_g, const float* __restrict__ bn_b,
    const float* __restrict__ bn_m, const float* __restrict__ bn_v,
    ushort_t* __restrict__ Xws) {
    __shared__ __align__(16) ushort_t Asm[82 * AST];
    __shared__ __align__(16) ushort_t Bsm[3 * 64 * AST];
    const int tid = threadIdx.x;
    const int n   = blockIdx.z;
    const int tm  = blockIdx.x * TM1;
    const int cb0 = blockIdx.y * TN1;
    const int wv = tid >> 6, lane = tid & 63, lrow = lane & 15, quad = lane >> 4;

    f32x4 acc[5];
#pragma unroll
    for (int i = 0; i < 5; ++i) acc[i] = (f32x4){0.f, 0.f, 0.f, 0.f};

    const ushort_t* ltbase = ltT + ((size_t)n * LTP_ + tm) * C_;
    for (int c0 = 0; c0 < C_; c0 += BK) {
        __syncthreads();
        // stage A: 82 rows x 32 bf16 (8B chunks): rows tm..tm+81 of padded ltT
        for (int idx = tid; idx < 82 * 8; idx += 256) {
            int r = idx >> 3, q = idx & 7;
            *(uint2*)&Asm[r * AST + q * 4] =
                *(const uint2*)(ltbase + (size_t)r * C_ + c0 + q * 4);
        }
        // stage B: 3 taps x 64 rows x 32 bf16
        for (int idx = tid; idx < 3 * 64 * 8; idx += 256) {
            int r = idx >> 3, q = idx & 7;  // r = k*64 + j
            *(uint2*)&Bsm[r * AST + q * 4] =
                *(const uint2*)(w1b + ((size_t)(r >> 6) * CB_ + cb0 + (r & 63)) * C_ + c0 + q * 4);
        }
        __syncthreads();
        bf16x8 bf[3];
#pragma unroll
        for (int k = 0; k < 3; ++k)
            bf[k] = *(const bf16x8*)&Bsm[(k * 64 + wv * 16 + lrow) * AST + quad * 8];
#pragma unroll
        for (int mf = 0; mf < 5; ++mf) {
#pragma unroll
            for (int k = 0; k < 3; ++k) {
                bf16x8 af = *(const bf16x8*)&Asm[(mf * 16 + lrow + k) * AST + quad * 8];
                acc[mf] = __builtin_amdgcn_mfma_f32_16x16x32_bf16(af, bf[k], acc[mf], 0, 0, 0);
            }
        }
    }
    // epilogue: BN+ReLU per cb, store bf16 to Xws[n][t][cb]
    int cb = cb0 + wv * 16 + lrow;
    float s  = bn_g[cb] * rsqrtf(bn_v[cb] + 1e-5f);
    float bo = bn_b[cb] - bn_m[cb] * s;
#pragma unroll
    for (int mf = 0; mf < 5; ++mf) {
#pragma unroll
        for (int r = 0; r < 4; ++r) {
            int t = tm + mf * 16 + quad * 4 + r;
            float v = fmaxf(fmaf(acc[mf][r], s, bo), 0.f);
            Xws[((size_t)n * LT_ + t) * CB_ + cb] = f2bf(v);
        }
    }
}

// ---------------- G2: gate[n][c][t] = sigmoid(W2 @ X), bf16 out
// M = c (tile 64, one 16-row slice per wave), N = t (tile 80), K = cb (BK 32)
#define TM2 64
#define TN2 80

__global__ __launch_bounds__(256) void k_gemm2(
    const ushort_t* __restrict__ Xws, const ushort_t* __restrict__ w2b,
    ushort_t* __restrict__ gate) {
    __shared__ __align__(16) ushort_t Asm[64 * AST];
    __shared__ __align__(16) ushort_t Bsm[80 * AST];
    const int tid = threadIdx.x;
    const int n  = blockIdx.z;
    const int cm = blockIdx.x * TM2;
    const int tt = blockIdx.y * TN2;
    const int wv = tid >> 6, lane = tid & 63, lrow = lane & 15, quad = lane >> 4;

    f32x4 acc[5];
#pragma unroll
    for (int i = 0; i < 5; ++i) acc[i] = (f32x4){0.f, 0.f, 0.f, 0.f};

    for (int k0 = 0; k0 < CB_; k0 += BK) {
        __syncthreads();
        for (int idx = tid; idx < 64 * 8; idx += 256) {  // A: w2 rows (c)
            int r = idx >> 3, q = idx & 7;
            *(uint2*)&Asm[r * AST + q * 4] =
                *(const uint2*)(w2b + (size_t)(cm + r) * CB_ + k0 + q * 4);
        }
        for (int idx = tid; idx < 80 * 8; idx += 256) {  // B: X rows (t)
            int r = idx >> 3, q = idx & 7;
            *(uint2*)&Bsm[r * AST + q * 4] =
                *(const uint2*)(Xws + ((size_t)n * LT_ + tt + r) * CB_ + k0 + q * 4);
        }
        __syncthreads();
        bf16x8 af = *(const bf16x8*)&Asm[(wv * 16 + lrow) * AST + quad * 8];
#pragma unroll
        for (int nf = 0; nf < 5; ++nf) {
            bf16x8 bfm = *(const bf16x8*)&Bsm[(nf * 16 + lrow) * AST + quad * 8];
            acc[nf] = __builtin_amdgcn_mfma_f32_16x16x32_bf16(af, bfm, acc[nf], 0, 0, 0);
        }
    }
#pragma unroll
    for (int nf = 0; nf < 5; ++nf) {
#pragma unroll
        for (int r = 0; r < 4; ++r) {
            int c = cm + wv * 16 + quad * 4 + r;
            int t = tt + nf * 16 + lrow;
            float g = 1.f / (1.f + __expf(-acc[nf][r]));
            gate[((size_t)n * C_ + c) * LT_ + t] = f2bf(g);
        }
    }
}

// ---------------- G3: out[n][c][t] = sum_i kern[n][c][i] * (lt*gate)[t+i-1]
__global__ __launch_bounds__(256) void k_final(
    const float* __restrict__ lt, const ushort_t* __restrict__ gate,
    const float* __restrict__ kern, float* __restrict__ out) {
    long long idx = (long long)blockIdx.x * 256 + threadIdx.x;  // over N*C*100
    int t0 = (int)(idx % 100) * 4;
    long long nc = idx / 100;
    const float*   ltp = lt   + (size_t)nc * LT_;
    const ushort_t* gp = gate + (size_t)nc * LT_;
    float4 kv = *(const float4*)(kern + (size_t)nc * 4);
    float nl[6];
#pragma unroll
    for (int j = -1; j <= 4; ++j) {
        int t = t0 + j;
        nl[j + 1] = (t >= 0 && t < LT_) ? ltp[t] * bf2f(gp[t]) : 0.f;
    }
    float4 o;
    o.x = kv.x * nl[0] + kv.y * nl[1] + kv.z * nl[2];
    o.y = kv.x * nl[1] + kv.y * nl[2] + kv.z * nl[3];
    o.z = kv.x * nl[2] + kv.y * nl[3] + kv.z * nl[4];
    o.w = kv.x * nl[3] + kv.y * nl[4] + kv.z * nl[5];
    *(float4*)(out + (size_t)nc * LT_ + t0) = o;
}

extern "C" void kernel_launch(void* const* d_in, const int* in_sizes, int n_in,
                              void* d_out, int out_size, void* d_ws, size_t ws_size,
                              hipStream_t stream) {
    const float* st   = (const float*)d_in[0];
    const float* lt   = (const float*)d_in[1];
    const float* g_w1 = (const float*)d_in[2];
    const float* g_bg = (const float*)d_in[3];
    const float* g_bb = (const float*)d_in[4];
    const float* g_bm = (const float*)d_in[5];
    const float* g_bv = (const float*)d_in[6];
    const float* g_w2 = (const float*)d_in[7];
    const float* l_w1 = (const float*)d_in[8];
    const float* l_bg = (const float*)d_in[9];
    const float* l_bb = (const float*)d_in[10];
    const float* l_bm = (const float*)d_in[11];
    const float* l_bv = (const float*)d_in[12];
    const float* l_w2 = (const float*)d_in[13];
    float* out = (float*)d_out;

    char* ws = (char*)d_ws;
    // workspace layout (bytes)
    float*    kern = (float*)(ws + 0);                    // 1,048,576
    ushort_t* w1b  = (ushort_t*)(ws + 1048576);           // 6,291,456
    ushort_t* w2b  = (ushort_t*)(ws + 7340032);           // 2,097,152
    ushort_t* Xws  = (ushort_t*)(ws + 9437184);           // 13,107,200
    ushort_t* ltT  = (ushort_t*)(ws + 22544384);          // 52,690,944
    ushort_t* gate = ltT;                                 // alias: ltT dead after G1

    k_global<<<dim3((N_ * C_) / 256), dim3(256), 0, stream>>>(
        st, g_w1, g_bg, g_bb, g_bm, g_bv, g_w2, kern);
    k_w1<<<dim3((CB_ * C_) / 256), dim3(256), 0, stream>>>(l_w1, w1b);
    k_w2<<<dim3((C_ * CB_) / 256), dim3(256), 0, stream>>>(l_w2, w2b);
    k_zero<<<dim3((N_ * C_) / 256), dim3(256), 0, stream>>>(ltT);
    k_transpose<<<dim3(13, C_ / 32, N_), dim3(256), 0, stream>>>(lt, ltT);
    k_gemm1<<<dim3(LT_ / TM1, CB_ / TN1, N_), dim3(256), 0, stream>>>(
        ltT, w1b, l_bg, l_bb, l_bm, l_bv, Xws);
    k_gemm2<<<dim3(C_ / TM2, LT_ / TN2, N_), dim3(256), 0, stream>>>(Xws, w2b, gate);
    k_final<<<dim3((N_ * C_ * (LT_ / 4)) / 256), dim3(256), 0, stream>>>(
        lt, gate, kern, out);
}

// Round 2
// 445.621 us; speedup vs baseline: 1.2617x; 1.2617x over previous
//
#include <hip/hip_runtime.h>
#include <hip/hip_bf16.h>

#define N_   32
#define C_   2048
#define ST_  16
#define H_   64      // ST*ALPHA
#define K_   3
#define CB_  512
#define LT_  400
#define LTP_ 402     // padded t rows (1 zero row each side)

using bf16x8 = __attribute__((ext_vector_type(8))) __bf16;
using f32x4  = __attribute__((ext_vector_type(4))) float;
typedef unsigned short ushort_t;

__device__ __forceinline__ unsigned short f2bf(float f) {
    unsigned int u = __float_as_uint(f);
    u = (u + 0x7fffu + ((u >> 16) & 1u)) >> 16;
    return (unsigned short)u;
}
__device__ __forceinline__ float bf2f(unsigned short h) {
    return __uint_as_float(((unsigned int)h) << 16);
}

// ---------------- P0: global branch -> per-(n,c) softmax kernel [NC,4] fp32
__global__ __launch_bounds__(256) void k_global(
    const float* __restrict__ st, const float* __restrict__ g_w1,
    const float* __restrict__ gam, const float* __restrict__ bet,
    const float* __restrict__ mean, const float* __restrict__ var,
    const float* __restrict__ g_w2, float* __restrict__ kern) {
    __shared__ float w1[H_][ST_];
    __shared__ float sc[H_], bi[H_];
    __shared__ float w2[K_][H_];
    int tid = threadIdx.x;
    for (int i = tid; i < H_ * ST_; i += 256) w1[i / ST_][i % ST_] = g_w1[i];
    if (tid < H_) {
        float s = gam[tid] * rsqrtf(var[tid] + 1e-5f);
        sc[tid] = s;
        bi[tid] = bet[tid] - mean[tid] * s;
    }
    for (int i = tid; i < K_ * H_; i += 256) w2[i / H_][i % H_] = g_w2[i];
    __syncthreads();
    int row = blockIdx.x * 256 + tid;  // n*C + c
    const float* p = st + (size_t)row * ST_;
    float s[ST_];
#pragma unroll
    for (int i = 0; i < ST_; ++i) s[i] = p[i];
    float lg0 = 0.f, lg1 = 0.f, lg2 = 0.f;
    for (int j = 0; j < H_; ++j) {
        float h = 0.f;
#pragma unroll
        for (int i = 0; i < ST_; ++i) h = fmaf(w1[j][i], s[i], h);
        h = fmaxf(fmaf(h, sc[j], bi[j]), 0.f);
        lg0 = fmaf(w2[0][j], h, lg0);
        lg1 = fmaf(w2[1][j], h, lg1);
        lg2 = fmaf(w2[2][j], h, lg2);
    }
    float m = fmaxf(lg0, fmaxf(lg1, lg2));
    float e0 = __expf(lg0 - m), e1 = __expf(lg1 - m), e2 = __expf(lg2 - m);
    float inv = 1.f / (e0 + e1 + e2);
    float4 o = make_float4(e0 * inv, e1 * inv, e2 * inv, 0.f);
    *(float4*)(kern + (size_t)row * 4) = o;
}

// ---------------- P1: transpose lt [n][c][t] fp32 -> ltT [n][t+1][c] bf16
__global__ __launch_bounds__(256) void k_transpose(
    const float* __restrict__ lt, ushort_t* __restrict__ ltT) {
    __shared__ float tile[32][33];
    int tt = blockIdx.x * 32;
    int cc = blockIdx.y * 32;
    int n  = blockIdx.z;
    const float* src = lt + ((size_t)n * C_ + cc) * LT_;
    int tx = threadIdx.x & 31, ty = threadIdx.x >> 5;  // ty 0..7
#pragma unroll
    for (int i = 0; i < 4; ++i) {
        int c = ty + i * 8;
        int t = tt + tx;
        tile[c][tx] = (t < LT_) ? src[(size_t)c * LT_ + t] : 0.f;
    }
    __syncthreads();
    ushort_t* dst = ltT + (size_t)n * LTP_ * C_;
#pragma unroll
    for (int i = 0; i < 4; ++i) {
        int tl = ty + i * 8;
        int t = tt + tl;
        if (t < LT_) dst[(size_t)(t + 1) * C_ + cc + tx] = f2bf(tile[tx][tl]);
    }
}

// zero the two pad rows of ltT
__global__ __launch_bounds__(256) void k_zero(ushort_t* __restrict__ ltT) {
    int i = blockIdx.x * 256 + threadIdx.x;  // over N*C
    int n = i >> 11, c = i & (C_ - 1);
    size_t base = (size_t)n * LTP_ * C_;
    ltT[base + c] = 0;
    ltT[base + (size_t)(LTP_ - 1) * C_ + c] = 0;
}

// ---------------- P2: repack l_w1 [cb][c][k] -> w1b[k][cb][c] bf16
__global__ __launch_bounds__(256) void k_w1(
    const float* __restrict__ l_w1, ushort_t* __restrict__ w1b) {
    int i = blockIdx.x * 256 + threadIdx.x;  // over CB*C
    float a = l_w1[(size_t)i * 3 + 0];
    float b = l_w1[(size_t)i * 3 + 1];
    float c = l_w1[(size_t)i * 3 + 2];
    w1b[0 * (size_t)CB_ * C_ + i] = f2bf(a);
    w1b[1 * (size_t)CB_ * C_ + i] = f2bf(b);
    w1b[2 * (size_t)CB_ * C_ + i] = f2bf(c);
}

// ---------------- P3: convert l_w2 [c][cb] -> bf16
__global__ __launch_bounds__(256) void k_w2(
    const float* __restrict__ l_w2, ushort_t* __restrict__ w2b) {
    int i = blockIdx.x * 256 + threadIdx.x;  // over C*CB
    w2b[i] = f2bf(l_w2[i]);
}

// ---------------- G1: X[n][t][cb] = ReLU(BN(sum_k W1k @ lt_shift_k)), bf16 out
// 128x128 tile, 2x2 waves (64x64/wave, 4x4 frags). M=t (ragged 400), N=cb, K=c.
#define BK  32
#define AST 40  // padded LDS row stride in ushorts: 80B rows, 16B-aligned

__global__ __launch_bounds__(256, 2) void k_gemm1(
    const ushort_t* __restrict__ ltT, const ushort_t* __restrict__ w1b,
    const float* __restrict__ bn_g, const float* __restrict__ bn_b,
    const float* __restrict__ bn_m, const float* __restrict__ bn_v,
    ushort_t* __restrict__ Xws) {
    __shared__ __align__(16) ushort_t Asm[130 * AST];
    __shared__ __align__(16) ushort_t Bsm[384 * AST];
    const int tid = threadIdx.x;
    const int n   = blockIdx.z;
    const int tm  = blockIdx.x * 128;   // padded-coords base row of A tile
    const int cb0 = blockIdx.y * 128;
    const int lane = tid & 63, lrow = lane & 15, quad = lane >> 4;
    const int wv = tid >> 6, wvM = wv & 1, wvN = wv >> 1;

    f32x4 acc[4][4];
#pragma unroll
    for (int i = 0; i < 4; ++i)
#pragma unroll
        for (int j = 0; j < 4; ++j) acc[i][j] = (f32x4){0.f, 0.f, 0.f, 0.f};

    // staging geometry: each thread owns (r0, q): r0 = tid>>2 in [0,64), q = tid&3
    const int r0 = tid >> 2, q = tid & 3;
    // A: rows r0, r0+64, (r0+128 for tid<8); global padded row = min(tm+r, 401)
    const ushort_t* aSrc0 = ltT + ((size_t)n * LTP_ + min(tm + r0, LTP_ - 1)) * C_ + q * 8;
    const ushort_t* aSrc1 = ltT + ((size_t)n * LTP_ + min(tm + r0 + 64, LTP_ - 1)) * C_ + q * 8;
    const ushort_t* aSrc2 = ltT + ((size_t)n * LTP_ + min(tm + r0 + 128, LTP_ - 1)) * C_ + q * 8;
    ushort_t* aDst0 = Asm + r0 * AST + q * 8;
    ushort_t* aDst1 = Asm + (r0 + 64) * AST + q * 8;
    ushort_t* aDst2 = Asm + (r0 + 128) * AST + q * 8;
    // B: 6 chunks of 64 rows; tap = chunk>>1, cb-local = r0 + 64*(chunk&1)
    const ushort_t* bSrc = w1b + (size_t)(cb0 + r0) * C_ + q * 8;
    ushort_t* bDst = Bsm + r0 * AST + q * 8;
    constexpr int OFFB[6] = {0, 64, 512, 576, 1024, 1088};  // * C_ elements

    for (int c0 = 0; c0 < C_; c0 += BK) {
        __syncthreads();
        *(uint4*)aDst0 = *(const uint4*)aSrc0;
        *(uint4*)aDst1 = *(const uint4*)aSrc1;
        if (tid < 8) *(uint4*)aDst2 = *(const uint4*)aSrc2;
#pragma unroll
        for (int i = 0; i < 6; ++i)
            *(uint4*)(bDst + i * 64 * AST) = *(const uint4*)(bSrc + (size_t)OFFB[i] * C_);
        aSrc0 += BK; aSrc1 += BK; aSrc2 += BK; bSrc += BK;
        __syncthreads();

        bf16x8 bfr[3][4];
#pragma unroll
        for (int k = 0; k < 3; ++k)
#pragma unroll
            for (int nf = 0; nf < 4; ++nf)
                bfr[k][nf] = *(const bf16x8*)&Bsm[(k * 128 + wvN * 64 + nf * 16 + lrow) * AST + quad * 8];
#pragma unroll
        for (int mf = 0; mf < 4; ++mf) {
            bf16x8 af[3];
#pragma unroll
            for (int k = 0; k < 3; ++k)
                af[k] = *(const bf16x8*)&Asm[(wvM * 64 + mf * 16 + lrow + k) * AST + quad * 8];
#pragma unroll
            for (int nf = 0; nf < 4; ++nf)
#pragma unroll
                for (int k = 0; k < 3; ++k)
                    acc[mf][nf] = __builtin_amdgcn_mfma_f32_16x16x32_bf16(af[k], bfr[k][nf], acc[mf][nf], 0, 0, 0);
        }
    }
    // epilogue: BN+ReLU per cb, store bf16 to Xws[n][t][cb], mask t<400
    float s[4], bo[4];
#pragma unroll
    for (int nf = 0; nf < 4; ++nf) {
        int cb = cb0 + wvN * 64 + nf * 16 + lrow;
        float sc = bn_g[cb] * rsqrtf(bn_v[cb] + 1e-5f);
        s[nf] = sc;
        bo[nf] = bn_b[cb] - bn_m[cb] * sc;
    }
    const int tBase = tm + wvM * 64 + quad * 4;  // actual t (padded row - 1 cancels shift)
#pragma unroll
    for (int mf = 0; mf < 4; ++mf) {
#pragma unroll
        for (int r = 0; r < 4; ++r) {
            int t = tBase + mf * 16 + r;
            if (t < LT_) {
#pragma unroll
                for (int nf = 0; nf < 4; ++nf) {
                    int cb = cb0 + wvN * 64 + nf * 16 + lrow;
                    float v = fmaxf(fmaf(acc[mf][nf][r], s[nf], bo[nf]), 0.f);
                    Xws[((size_t)n * LT_ + t) * CB_ + cb] = f2bf(v);
                }
            }
        }
    }
}

// ---------------- G2: gate[n][c][t] = sigmoid(W2 @ X), bf16 out
// 128x128 tile, 2x2 waves. M=c, N=t (ragged 400), K=cb.
__global__ __launch_bounds__(256, 2) void k_gemm2(
    const ushort_t* __restrict__ Xws, const ushort_t* __restrict__ w2b,
    ushort_t* __restrict__ gate) {
    __shared__ __align__(16) ushort_t Asm[128 * AST];
    __shared__ __align__(16) ushort_t Bsm[128 * AST];
    const int tid = threadIdx.x;
    const int n  = blockIdx.z;
    const int cm = blockIdx.x * 128;
    const int tt = blockIdx.y * 128;
    const int lane = tid & 63, lrow = lane & 15, quad = lane >> 4;
    const int wv = tid >> 6, wvM = wv & 1, wvN = wv >> 1;

    f32x4 acc[4][4];
#pragma unroll
    for (int i = 0; i < 4; ++i)
#pragma unroll
        for (int j = 0; j < 4; ++j) acc[i][j] = (f32x4){0.f, 0.f, 0.f, 0.f};

    const int r0 = tid >> 2, q = tid & 3;
    const ushort_t* aSrc0 = w2b + (size_t)(cm + r0) * CB_ + q * 8;
    const ushort_t* aSrc1 = w2b + (size_t)(cm + r0 + 64) * CB_ + q * 8;
    const ushort_t* bSrc0 = Xws + ((size_t)n * LT_ + min(tt + r0, LT_ - 1)) * CB_ + q * 8;
    const ushort_t* bSrc1 = Xws + ((size_t)n * LT_ + min(tt + r0 + 64, LT_ - 1)) * CB_ + q * 8;
    ushort_t* aDst0 = Asm + r0 * AST + q * 8;
    ushort_t* aDst1 = Asm + (r0 + 64) * AST + q * 8;
    ushort_t* bDst0 = Bsm + r0 * AST + q * 8;
    ushort_t* bDst1 = Bsm + (r0 + 64) * AST + q * 8;

    for (int k0 = 0; k0 < CB_; k0 += BK) {
        __syncthreads();
        *(uint4*)aDst0 = *(const uint4*)aSrc0;
        *(uint4*)aDst1 = *(const uint4*)aSrc1;
        *(uint4*)bDst0 = *(const uint4*)bSrc0;
        *(uint4*)bDst1 = *(const uint4*)bSrc1;
        aSrc0 += BK; aSrc1 += BK; bSrc0 += BK; bSrc1 += BK;
        __syncthreads();

        bf16x8 af[4], bfm[4];
#pragma unroll
        for (int mf = 0; mf < 4; ++mf)
            af[mf] = *(const bf16x8*)&Asm[(wvM * 64 + mf * 16 + lrow) * AST + quad * 8];
#pragma unroll
        for (int nf = 0; nf < 4; ++nf)
            bfm[nf] = *(const bf16x8*)&Bsm[(wvN * 64 + nf * 16 + lrow) * AST + quad * 8];
#pragma unroll
        for (int mf = 0; mf < 4; ++mf)
#pragma unroll
            for (int nf = 0; nf < 4; ++nf)
                acc[mf][nf] = __builtin_amdgcn_mfma_f32_16x16x32_bf16(af[mf], bfm[nf], acc[mf][nf], 0, 0, 0);
    }
#pragma unroll
    for (int mf = 0; mf < 4; ++mf) {
#pragma unroll
        for (int r = 0; r < 4; ++r) {
            int c = cm + wvM * 64 + mf * 16 + quad * 4 + r;
#pragma unroll
            for (int nf = 0; nf < 4; ++nf) {
                int t = tt + wvN * 64 + nf * 16 + lrow;
                if (t < LT_) {
                    float g = 1.f / (1.f + __expf(-acc[mf][nf][r]));
                    gate[((size_t)n * C_ + c) * LT_ + t] = f2bf(g);
                }
            }
        }
    }
}

// ---------------- G3: out[n][c][t] = sum_i kern[n][c][i] * (lt*gate)[t+i-1]
__global__ __launch_bounds__(256) void k_final(
    const float* __restrict__ lt, const ushort_t* __restrict__ gate,
    const float* __restrict__ kern, float* __restrict__ out) {
    long long idx = (long long)blockIdx.x * 256 + threadIdx.x;  // over N*C*100
    int t0 = (int)(idx % 100) * 4;
    long long nc = idx / 100;
    const float*   ltp = lt   + (size_t)nc * LT_;
    const ushort_t* gp = gate + (size_t)nc * LT_;
    float4 kv = *(const float4*)(kern + (size_t)nc * 4);
    float nl[6];
#pragma unroll
    for (int j = -1; j <= 4; ++j) {
        int t = t0 + j;
        nl[j + 1] = (t >= 0 && t < LT_) ? ltp[t] * bf2f(gp[t]) : 0.f;
    }
    float4 o;
    o.x = kv.x * nl[0] + kv.y * nl[1] + kv.z * nl[2];
    o.y = kv.x * nl[1] + kv.y * nl[2] + kv.z * nl[3];
    o.z = kv.x * nl[2] + kv.y * nl[3] + kv.z * nl[4];
    o.w = kv.x * nl[3] + kv.y * nl[4] + kv.z * nl[5];
    *(float4*)(out + (size_t)nc * LT_ + t0) = o;
}

extern "C" void kernel_launch(void* const* d_in, const int* in_sizes, int n_in,
                              void* d_out, int out_size, void* d_ws, size_t ws_size,
                              hipStream_t stream) {
    const float* st   = (const float*)d_in[0];
    const float* lt   = (const float*)d_in[1];
    const float* g_w1 = (const float*)d_in[2];
    const float* g_bg = (const float*)d_in[3];
    const float* g_bb = (const float*)d_in[4];
    const float* g_bm = (const float*)d_in[5];
    const float* g_bv = (const float*)d_in[6];
    const float* g_w2 = (const float*)d_in[7];
    const float* l_w1 = (const float*)d_in[8];
    const float* l_bg = (const float*)d_in[9];
    const float* l_bb = (const float*)d_in[10];
    const float* l_bm = (const float*)d_in[11];
    const float* l_bv = (const float*)d_in[12];
    const float* l_w2 = (const float*)d_in[13];
    float* out = (float*)d_out;

    char* ws = (char*)d_ws;
    // workspace layout (bytes)
    float*    kern = (float*)(ws + 0);                    // 1,048,576
    ushort_t* w1b  = (ushort_t*)(ws + 1048576);           // 6,291,456
    ushort_t* w2b  = (ushort_t*)(ws + 7340032);           // 2,097,152
    ushort_t* Xws  = (ushort_t*)(ws + 9437184);           // 13,107,200
    ushort_t* ltT  = (ushort_t*)(ws + 22544384);          // 52,690,944
    ushort_t* gate = ltT;                                 // alias: ltT dead after G1

    k_global<<<dim3((N_ * C_) / 256), dim3(256), 0, stream>>>(
        st, g_w1, g_bg, g_bb, g_bm, g_bv, g_w2, kern);
    k_w1<<<dim3((CB_ * C_) / 256), dim3(256), 0, stream>>>(l_w1, w1b);
    k_w2<<<dim3((C_ * CB_) / 256), dim3(256), 0, stream>>>(l_w2, w2b);
    k_zero<<<dim3((N_ * C_) / 256), dim3(256), 0, stream>>>(ltT);
    k_transpose<<<dim3(13, C_ / 32, N_), dim3(256), 0, stream>>>(lt, ltT);
    k_gemm1<<<dim3(4, 4, N_), dim3(256), 0, stream>>>(
        ltT, w1b, l_bg, l_bb, l_bm, l_bv, Xws);
    k_gemm2<<<dim3(C_ / 128, 4, N_), dim3(256), 0, stream>>>(Xws, w2b, gate);
    k_final<<<dim3((N_ * C_ * (LT_ / 4)) / 256), dim3(256), 0, stream>>>(
        lt, gate, kern, out);
}